// Round 1
// baseline (281.558 us; speedup 1.0000x reference)
//
#include <hip/hip_runtime.h>
#include <math.h>

#define TLEN 512
#define NCH  128
#define KP   4
#define PMAXV 64
#define CMAXV 32
#define MINP 16
#define NSEQ 4096   // B*N = 32*128
#define OUTG ((size_t)NSEQ * KP * CMAXV * PMAXV)   // 33,554,432

// One block per sequence. 256 threads.
// Phase 1: load strided column into LDS (float).
// Phase 2: 512-pt complex radix-2 DIT FFT in fp64 (imag=0 input).
// Phase 3: amplitudes (fp64), DC zeroed; 4x argmax reduction w/ lowest-index tie-break.
// Phase 4: compute P/cycles/base; write kamp.
// Phase 5: gather + mask, float4 coalesced stores (64 KB per block).
__global__ __launch_bounds__(256) void periodicity_kernel(
    const float* __restrict__ x,
    float* __restrict__ out_g,
    float* __restrict__ out_m,
    float* __restrict__ out_a)
{
    const int s   = blockIdx.x;    // sequence id 0..4095
    const int tid = threadIdx.x;   // 0..255

    __shared__ float   seqf[TLEN];
    __shared__ double2 X[TLEN];
    __shared__ double2 W[TLEN / 2];
    __shared__ double  amp[TLEN / 2 + 1];
    __shared__ double  rv[256];
    __shared__ int     ri[256];
    __shared__ double  bestv[KP];
    __shared__ int     besti[KP];
    __shared__ int     Ps[KP], Cs[KP], Bs[KP];

    // ---- Phase 1: load column (x[b, :, n]) ----
    const int b = s >> 7;          // / NCH
    const int n = s & (NCH - 1);
    const float* col = x + (size_t)b * TLEN * NCH + n;
    for (int i = tid; i < TLEN; i += 256)
        seqf[i] = col[(size_t)i * NCH];

    // twiddles: W[j] = exp(-2*pi*i*j/512), j = 0..255  (one per thread)
    {
        double ang = -6.283185307179586476925286766559 * (double)tid / (double)TLEN;
        double sv, cv;
        sincos(ang, &sv, &cv);
        W[tid] = make_double2(cv, sv);
    }
    __syncthreads();

    // ---- Phase 2: bit-reverse load + radix-2 DIT FFT ----
    for (int i = tid; i < TLEN; i += 256) {
        int r = (int)(__brev((unsigned)i) >> 23);   // 9-bit reverse
        X[i] = make_double2((double)seqf[r], 0.0);
    }
    __syncthreads();

    for (int st = 1; st <= 9; ++st) {
        const int half = 1 << (st - 1);
        const int pos  = tid & (half - 1);
        const int i1   = ((tid >> (st - 1)) << st) + pos;
        const int i2   = i1 + half;
        const double2 wv = W[pos << (9 - st)];
        const double2 a  = X[i1];
        const double2 c  = X[i2];
        const double tr = wv.x * c.x - wv.y * c.y;
        const double ti = wv.x * c.y + wv.y * c.x;
        X[i1] = make_double2(a.x + tr, a.y + ti);
        X[i2] = make_double2(a.x - tr, a.y - ti);
        __syncthreads();
    }

    // ---- Phase 3: amplitudes, DC zeroed ----
    {
        double2 v = X[tid];
        amp[tid] = (tid == 0) ? 0.0 : sqrt(v.x * v.x + v.y * v.y);
        if (tid == 0) {
            double2 vn = X[TLEN / 2];
            amp[TLEN / 2] = sqrt(vn.x * vn.x + vn.y * vn.y);
        }
    }
    __syncthreads();

    // top-4 via 4 sequential argmax reductions; ties -> lowest index (jax top_k)
    for (int q = 0; q < KP; ++q) {
        double v = amp[tid];
        int    idx = tid;
        if (tid == 0) {
            double v2 = amp[TLEN / 2];
            if (v2 > v) { v = v2; idx = TLEN / 2; }  // tie keeps idx 0 (smaller)
        }
        rv[tid] = v; ri[tid] = idx;
        __syncthreads();
        for (int off = 128; off > 0; off >>= 1) {
            if (tid < off) {
                double ov = rv[tid + off];
                int    oi = ri[tid + off];
                if (ov > rv[tid] || (ov == rv[tid] && oi < ri[tid])) {
                    rv[tid] = ov; ri[tid] = oi;
                }
            }
            __syncthreads();
        }
        if (tid == 0) {
            bestv[q] = rv[0];
            besti[q] = ri[0];
            amp[ri[0]] = -1.0;   // exclude from next pass (amps >= 0)
        }
        __syncthreads();
    }

    // ---- Phase 4: periods / cycles / base; kamp out ----
    if (tid < KP) {
        int ki = besti[tid];
        if (ki < 1) ki = 1;
        int P = TLEN / ki;
        P = P < MINP ? MINP : (P > PMAXV ? PMAXV : P);
        int cyc = TLEN / P;            // 8..32, always >= 1
        Ps[tid] = P;
        Cs[tid] = cyc;
        Bs[tid] = TLEN - cyc * P;      // max(T - take, 0); take <= T always
        out_a[(size_t)s * KP + tid] = (float)bestv[tid];
    }
    __syncthreads();

    // ---- Phase 5: gather + mask writes ----
    float* og = out_g + (size_t)s * (KP * CMAXV * PMAXV);
    float* om = out_m + (size_t)s * (KP * CMAXV * PMAXV);
    const int pp = (tid & 15) << 2;     // p offset 0..60 step 4
    for (int r = tid >> 4; r < KP * CMAXV; r += 16) {
        const int k = r >> 5;            // / CMAXV
        const int c = r & (CMAXV - 1);
        const int P = Ps[k], cyc = Cs[k], base = Bs[k];
        float4 g = make_float4(0.f, 0.f, 0.f, 0.f);
        float4 m = make_float4(0.f, 0.f, 0.f, 0.f);
        if (c < cyc) {
            const int idx = base + c * P + pp;   // in-bounds whenever p < P
            if (pp     < P) { g.x = seqf[idx];     m.x = 1.f; }
            if (pp + 1 < P) { g.y = seqf[idx + 1]; m.y = 1.f; }
            if (pp + 2 < P) { g.z = seqf[idx + 2]; m.z = 1.f; }
            if (pp + 3 < P) { g.w = seqf[idx + 3]; m.w = 1.f; }
        }
        *(float4*)(og + r * PMAXV + pp) = g;
        *(float4*)(om + r * PMAXV + pp) = m;
    }
}

extern "C" void kernel_launch(void* const* d_in, const int* in_sizes, int n_in,
                              void* d_out, int out_size, void* d_ws, size_t ws_size,
                              hipStream_t stream) {
    const float* x = (const float*)d_in[0];
    float* out = (float*)d_out;
    float* og = out;              // gathered: [B,N,K,Cmax,Pmax]
    float* om = out + OUTG;       // mask:     same shape
    float* oa = om + OUTG;        // kamp:     [B,N,K]
    periodicity_kernel<<<dim3(NSEQ), dim3(256), 0, stream>>>(x, og, om, oa);
}

// Round 2
// 277.387 us; speedup vs baseline: 1.0150x; 1.0150x over previous
//
#include <hip/hip_runtime.h>
#include <math.h>

#define TLEN 512
#define NCH  128
#define KP   4
#define PMAXV 64
#define CMAXV 32
#define MINP 16
#define NSEQ 4096   // B*N = 32*128
#define OUTG ((size_t)NSEQ * KP * CMAXV * PMAXV)   // 33,554,432

// One block (256 thr = 4 waves) per sequence.
// Barrier-minimized: 6 __syncthreads total.
//  - FFT stages 1..7 are intra-wave (butterfly span < 64 within wave-owned
//    128-point chunks after wave-local bit-reverse) -> no block barrier;
//    same-wave LDS ops are processed in order (wave_barrier stops compiler
//    reordering only).
//  - top-4 argmax done by wave 0 with shfl_xor butterflies (no barriers).
__global__ __launch_bounds__(256) void periodicity_kernel(
    const float* __restrict__ x,
    float* __restrict__ out_g,
    float* __restrict__ out_m,
    float* __restrict__ out_a)
{
    const int s    = blockIdx.x;     // sequence id 0..4095
    const int tid  = threadIdx.x;    // 0..255
    const int lane = tid & 63;
    const int wave = tid >> 6;

    __shared__ float   seqf[TLEN];
    __shared__ double2 X[TLEN];
    __shared__ double2 W[TLEN / 2];
    __shared__ double  amp[TLEN / 2 + 1];
    __shared__ double  bestv[KP];
    __shared__ int     besti[KP];
    __shared__ int     Ps[KP], Cs[KP], Bs[KP];

    // ---- Phase 1: load column x[b, :, n] + twiddles ----
    const int b = s >> 7;            // / NCH
    const int n = s & (NCH - 1);
    const float* col = x + (size_t)b * TLEN * NCH + n;
    for (int i = tid; i < TLEN; i += 256)
        seqf[i] = col[(size_t)i * NCH];
    {
        double ang = -6.283185307179586476925286766559 * (double)tid / (double)TLEN;
        double sv, cv;
        sincos(ang, &sv, &cv);
        W[tid] = make_double2(cv, sv);
    }
    __syncthreads();   // B1: seqf + W ready

    // ---- Phase 2: wave-local bit-reverse scatter into own 128-pt chunk ----
    {
        const int base = wave << 7;                  // 128*wave
        int i0 = base + lane, i1 = base + 64 + lane;
        int r0 = (int)(__brev((unsigned)i0) >> 23);  // 9-bit reverse
        int r1 = (int)(__brev((unsigned)i1) >> 23);
        X[i0] = make_double2((double)seqf[r0], 0.0);
        X[i1] = make_double2((double)seqf[r1], 0.0);
    }
    __builtin_amdgcn_wave_barrier();

    // stages 1..7: butterflies stay inside the wave's 128-pt chunk
    #pragma unroll
    for (int st = 1; st <= 7; ++st) {
        const int half = 1 << (st - 1);
        const int pos  = tid & (half - 1);
        const int i1   = ((tid >> (st - 1)) << st) + pos;
        const int i2   = i1 + half;
        const double2 wv = W[pos << (9 - st)];
        const double2 a  = X[i1];
        const double2 c  = X[i2];
        const double tr = wv.x * c.x - wv.y * c.y;
        const double ti = wv.x * c.y + wv.y * c.x;
        X[i1] = make_double2(a.x + tr, a.y + ti);
        X[i2] = make_double2(a.x - tr, a.y - ti);
        __builtin_amdgcn_wave_barrier();
    }

    // stages 8,9 cross waves
    #pragma unroll
    for (int st = 8; st <= 9; ++st) {
        __syncthreads();             // B2, B3
        const int half = 1 << (st - 1);
        const int pos  = tid & (half - 1);
        const int i1   = ((tid >> (st - 1)) << st) + pos;
        const int i2   = i1 + half;
        const double2 wv = W[pos << (9 - st)];
        const double2 a  = X[i1];
        const double2 c  = X[i2];
        const double tr = wv.x * c.x - wv.y * c.y;
        const double ti = wv.x * c.y + wv.y * c.x;
        X[i1] = make_double2(a.x + tr, a.y + ti);
        X[i2] = make_double2(a.x - tr, a.y - ti);
    }
    __syncthreads();                 // B4: X final

    // ---- Phase 3: amplitudes, DC zeroed ----
    {
        double2 v = X[tid];
        amp[tid] = (tid == 0) ? 0.0 : sqrt(v.x * v.x + v.y * v.y);
        if (tid == 0) {
            double2 vn = X[TLEN / 2];
            amp[TLEN / 2] = sqrt(vn.x * vn.x + vn.y * vn.y);
        }
    }
    __syncthreads();                 // B5: amp ready

    // ---- Phase 4: top-4 by wave 0 only (shfl butterflies, no barriers) ----
    if (wave == 0) {
        for (int q = 0; q < KP; ++q) {
            // local candidate, scanning increasing index w/ strict > :
            // keeps the SMALLEST index on exact ties (jax top_k semantics)
            double v  = amp[lane];
            int    vi = lane;
            #pragma unroll
            for (int j = 1; j < 4; ++j) {
                double u = amp[lane + 64 * j];
                if (u > v) { v = u; vi = lane + 64 * j; }
            }
            if (lane == 0) {
                double u = amp[256];
                if (u > v) { v = u; vi = 256; }
            }
            // 64-lane butterfly argmax with smallest-index tie-break
            #pragma unroll
            for (int off = 32; off > 0; off >>= 1) {
                double ov = __shfl_xor(v, off, 64);
                int    oi = __shfl_xor(vi, off, 64);
                if (ov > v || (ov == v && oi < vi)) { v = ov; vi = oi; }
            }
            if (lane == 0) {
                bestv[q] = v;
                besti[q] = vi;
                amp[vi] = -1.0;      // exclude (amps >= 0); same-wave LDS in order
            }
            __builtin_amdgcn_wave_barrier();
        }
        // periods / cycles / base + kamp out (lanes 0..3)
        if (lane < KP) {
            int ki = besti[lane];
            if (ki < 1) ki = 1;
            int P = TLEN / ki;
            P = P < MINP ? MINP : (P > PMAXV ? PMAXV : P);
            int cyc = TLEN / P;      // 8..32
            Ps[lane] = P;
            Cs[lane] = cyc;
            Bs[lane] = TLEN - cyc * P;
            out_a[(size_t)s * KP + lane] = (float)bestv[lane];
        }
    }
    __syncthreads();                 // B6: params ready

    // ---- Phase 5: gather + mask, float4 coalesced stores ----
    float* og = out_g + (size_t)s * (KP * CMAXV * PMAXV);
    float* om = out_m + (size_t)s * (KP * CMAXV * PMAXV);
    const int pp = (tid & 15) << 2;      // p offset 0..60 step 4
    for (int r = tid >> 4; r < KP * CMAXV; r += 16) {
        const int k = r >> 5;            // / CMAXV
        const int c = r & (CMAXV - 1);
        const int P = Ps[k], cyc = Cs[k], base = Bs[k];
        float4 g = make_float4(0.f, 0.f, 0.f, 0.f);
        float4 m = make_float4(0.f, 0.f, 0.f, 0.f);
        if (c < cyc) {
            const int idx = base + c * P + pp;   // in-bounds whenever p < P
            if (pp     < P) { g.x = seqf[idx];     m.x = 1.f; }
            if (pp + 1 < P) { g.y = seqf[idx + 1]; m.y = 1.f; }
            if (pp + 2 < P) { g.z = seqf[idx + 2]; m.z = 1.f; }
            if (pp + 3 < P) { g.w = seqf[idx + 3]; m.w = 1.f; }
        }
        *(float4*)(og + r * PMAXV + pp) = g;
        *(float4*)(om + r * PMAXV + pp) = m;
    }
}

extern "C" void kernel_launch(void* const* d_in, const int* in_sizes, int n_in,
                              void* d_out, int out_size, void* d_ws, size_t ws_size,
                              hipStream_t stream) {
    const float* x = (const float*)d_in[0];
    float* out = (float*)d_out;
    float* og = out;              // gathered: [B,N,K,Cmax,Pmax]
    float* om = out + OUTG;       // mask:     same shape
    float* oa = om + OUTG;        // kamp:     [B,N,K]
    periodicity_kernel<<<dim3(NSEQ), dim3(256), 0, stream>>>(x, og, om, oa);
}